// Round 7
// baseline (225.736 us; speedup 1.0000x reference)
//
#include <hip/hip_runtime.h>

// x: [T=63, B=1, H=16, S=384, D=128] f32
// y: [T=63, B=1, H=16, D=128, S=384] f32
// out: [63, 1, 16, 384, 384] f32 = broadcast of per-head (mean_t x) @ (mean_t y)
#define T_DIM 63
#define H_DIM 16
#define S_DIM 384
#define D_DIM 128
#define SLICE_ELEMS (H_DIM * S_DIM * D_DIM)        // 786432 floats per t-slice
#define SLICE_F4    (SLICE_ELEMS / 4)              // 196608
#define OUT_TSTRIDE (H_DIM * S_DIM * S_DIM)        // 2359296 floats per t-slice of out
#define W_F4        (OUT_TSTRIDE / 4)              // 589824 float4 per t-slice

typedef float f32x4 __attribute__((ext_vector_type(4)));

// Kernel 1: temporal mean over T for both x and y. Pure read-bound (396 MB).
// PLAIN loads this round (A/B vs R4's nontemporal): every reference stream
// that reaches ~6.3-6.9 TB/s (m13 copy, rocclr fill) uses plain accesses.
__global__ __launch_bounds__(256) void treduce_kernel(
    const float* __restrict__ x, const float* __restrict__ y,
    float* __restrict__ xb, float* __restrict__ yb) {
  int tid = blockIdx.x * 256 + threadIdx.x;      // 0 .. 2*SLICE_F4-1
  const f32x4* src;
  f32x4* dst;
  if (tid < SLICE_F4) {
    src = reinterpret_cast<const f32x4*>(x) + tid;
    dst = reinterpret_cast<f32x4*>(xb) + tid;
  } else {
    tid -= SLICE_F4;
    src = reinterpret_cast<const f32x4*>(y) + tid;
    dst = reinterpret_cast<f32x4*>(yb) + tid;
  }
  f32x4 acc = (f32x4)0.f;
#pragma unroll 9
  for (int t = 0; t < T_DIM; ++t) {
    f32x4 v = src[(size_t)t * SLICE_F4];
    acc += v;
  }
  acc *= (1.0f / (float)T_DIM);
  *dst = acc;
}

// Kernel 2: per-head GEMM w[h] = xb[h] (384x128) @ yb[h] (128x384), computed
// ONCE, written straight into out's t=0 slice. grid=(6,6,16), block=256.
__global__ __launch_bounds__(256) void gemm_kernel(
    const float* __restrict__ xb, const float* __restrict__ yb,
    float* __restrict__ out) {
  __shared__ float As[64][132];   // padded: 2-way max bank aliasing (free)
  __shared__ float Bs[128][64];

  const int h  = blockIdx.z;
  const int by = blockIdx.y;
  const int bx = blockIdx.x;
  const int t  = threadIdx.x;

  const float* A = xb + (size_t)h * S_DIM * D_DIM;  // [384][128] row-major
  const float* B = yb + (size_t)h * D_DIM * S_DIM;  // [128][384] row-major

#pragma unroll
  for (int it = 0; it < 8; ++it) {
    int l = t + it * 256;
    int row = l >> 5;        // 32 float4 per row
    int c4  = l & 31;
    float4 v = *reinterpret_cast<const float4*>(A + (size_t)(by * 64 + row) * D_DIM + c4 * 4);
    *reinterpret_cast<float4*>(&As[row][c4 * 4]) = v;
  }
#pragma unroll
  for (int it = 0; it < 8; ++it) {
    int l = t + it * 256;
    int k  = l >> 4;         // 16 float4 per row
    int c4 = l & 15;
    float4 v = *reinterpret_cast<const float4*>(B + (size_t)k * S_DIM + bx * 64 + c4 * 4);
    *reinterpret_cast<float4*>(&Bs[k][c4 * 4]) = v;
  }
  __syncthreads();

  const int tx = t & 15;
  const int ty = t >> 4;
  const int r0 = ty * 4;
  const int c0 = tx * 4;

  float acc[4][4];
#pragma unroll
  for (int i = 0; i < 4; ++i)
#pragma unroll
    for (int j = 0; j < 4; ++j) acc[i][j] = 0.f;

#pragma unroll 4
  for (int k = 0; k < D_DIM; ++k) {
    float a0 = As[r0 + 0][k];
    float a1 = As[r0 + 1][k];
    float a2 = As[r0 + 2][k];
    float a3 = As[r0 + 3][k];
    float4 b = *reinterpret_cast<const float4*>(&Bs[k][c0]);
    acc[0][0] += a0 * b.x; acc[0][1] += a0 * b.y; acc[0][2] += a0 * b.z; acc[0][3] += a0 * b.w;
    acc[1][0] += a1 * b.x; acc[1][1] += a1 * b.y; acc[1][2] += a1 * b.z; acc[1][3] += a1 * b.w;
    acc[2][0] += a2 * b.x; acc[2][1] += a2 * b.y; acc[2][2] += a2 * b.z; acc[2][3] += a2 * b.w;
    acc[3][0] += a3 * b.x; acc[3][1] += a3 * b.y; acc[3][2] += a3 * b.z; acc[3][3] += a3 * b.w;
  }

  // Write the tile ONCE into the t=0 slice (k3 re-reads it: 9.4 MB, L2-hot).
  float* o = out + (size_t)h * S_DIM * S_DIM + (size_t)(by * 64 + r0) * S_DIM + bx * 64 + c0;
#pragma unroll
  for (int i = 0; i < 4; ++i) {
    *reinterpret_cast<float4*>(o + (size_t)i * S_DIM) =
        make_float4(acc[i][0], acc[i][1], acc[i][2], acc[i][3]);
  }
}

// Kernel 3: pure broadcast. Thread i reads float4 i of the t=0 slice once
// (9.4 MB total, L2-dirty from k2) and stores it to t=1..62 (584 MB writes).
// PLAIN stores this round (A/B vs R4's nontemporal).
__global__ __launch_bounds__(256) void bcast_kernel(float* __restrict__ out) {
  int i = blockIdx.x * 256 + threadIdx.x;   // 0 .. W_F4-1
  f32x4* o4 = reinterpret_cast<f32x4*>(out);
  f32x4 v = o4[i];
#pragma unroll 31
  for (int t = 1; t < T_DIM; ++t) {
    o4[(size_t)t * W_F4 + i] = v;
  }
}

extern "C" void kernel_launch(void* const* d_in, const int* in_sizes, int n_in,
                              void* d_out, int out_size, void* d_ws, size_t ws_size,
                              hipStream_t stream) {
  const float* x = (const float*)d_in[0];
  const float* y = (const float*)d_in[1];
  float* out = (float*)d_out;

  float* xb = (float*)d_ws;                 // 786432 floats
  float* yb = xb + SLICE_ELEMS;             // 786432 floats (6 MB total)

  treduce_kernel<<<dim3(2 * SLICE_F4 / 256), dim3(256), 0, stream>>>(x, y, xb, yb);
  gemm_kernel<<<dim3(6, 6, H_DIM), dim3(256), 0, stream>>>(xb, yb, out);
  bcast_kernel<<<dim3(W_F4 / 256), dim3(256), 0, stream>>>(out);
}

// Round 8
// 185.844 us; speedup vs baseline: 1.2147x; 1.2147x over previous
//
#include <hip/hip_runtime.h>

// x: [T=63, B=1, H=16, S=384, D=128] f32
// y: [T=63, B=1, H=16, D=128, S=384] f32
// out: [63, 1, 16, 384, 384] f32 = broadcast of per-head (mean_t x) @ (mean_t y)
#define T_DIM 63
#define H_DIM 16
#define S_DIM 384
#define D_DIM 128
#define SLICE_ELEMS (H_DIM * S_DIM * D_DIM)        // 786432 floats per t-slice
#define SLICE_F4    (SLICE_ELEMS / 4)              // 196608
#define OUT_TSTRIDE (H_DIM * S_DIM * S_DIM)        // 2359296 floats per t-slice of out
#define W_F4        (OUT_TSTRIDE / 4)              // 589824 float4 per t-slice

typedef float f32x4 __attribute__((ext_vector_type(4)));

// Kernel 1: temporal mean over T for both x and y. Pure read-bound (396 MB).
// nt loads (R7 A/B proved nt is worth ~15-20% on these streams).
__global__ __launch_bounds__(256) void treduce_kernel(
    const float* __restrict__ x, const float* __restrict__ y,
    float* __restrict__ xb, float* __restrict__ yb) {
  int tid = blockIdx.x * 256 + threadIdx.x;      // 0 .. 2*SLICE_F4-1
  const f32x4* src;
  f32x4* dst;
  if (tid < SLICE_F4) {
    src = reinterpret_cast<const f32x4*>(x) + tid;
    dst = reinterpret_cast<f32x4*>(xb) + tid;
  } else {
    tid -= SLICE_F4;
    src = reinterpret_cast<const f32x4*>(y) + tid;
    dst = reinterpret_cast<f32x4*>(yb) + tid;
  }
  f32x4 acc = (f32x4)0.f;
#pragma unroll 9
  for (int t = 0; t < T_DIM; ++t) {
    f32x4 v = __builtin_nontemporal_load(src + (size_t)t * SLICE_F4);
    acc += v;
  }
  acc *= (1.0f / (float)T_DIM);
  *dst = acc;
}

// Kernel 2: per-head GEMM w[h] = xb[h] (384x128) @ yb[h] (128x384), computed
// ONCE, written straight into out's t=0 slice. grid=(6,6,16), block=256.
// (byte-identical to R4)
__global__ __launch_bounds__(256) void gemm_kernel(
    const float* __restrict__ xb, const float* __restrict__ yb,
    float* __restrict__ out) {
  __shared__ float As[64][132];   // padded: 2-way max bank aliasing (free)
  __shared__ float Bs[128][64];

  const int h  = blockIdx.z;
  const int by = blockIdx.y;
  const int bx = blockIdx.x;
  const int t  = threadIdx.x;

  const float* A = xb + (size_t)h * S_DIM * D_DIM;  // [384][128] row-major
  const float* B = yb + (size_t)h * D_DIM * S_DIM;  // [128][384] row-major

#pragma unroll
  for (int it = 0; it < 8; ++it) {
    int l = t + it * 256;
    int row = l >> 5;        // 32 float4 per row
    int c4  = l & 31;
    float4 v = *reinterpret_cast<const float4*>(A + (size_t)(by * 64 + row) * D_DIM + c4 * 4);
    *reinterpret_cast<float4*>(&As[row][c4 * 4]) = v;
  }
#pragma unroll
  for (int it = 0; it < 8; ++it) {
    int l = t + it * 256;
    int k  = l >> 4;         // 16 float4 per row
    int c4 = l & 15;
    float4 v = *reinterpret_cast<const float4*>(B + (size_t)k * S_DIM + bx * 64 + c4 * 4);
    *reinterpret_cast<float4*>(&Bs[k][c4 * 4]) = v;
  }
  __syncthreads();

  const int tx = t & 15;
  const int ty = t >> 4;
  const int r0 = ty * 4;
  const int c0 = tx * 4;

  float acc[4][4];
#pragma unroll
  for (int i = 0; i < 4; ++i)
#pragma unroll
    for (int j = 0; j < 4; ++j) acc[i][j] = 0.f;

#pragma unroll 4
  for (int k = 0; k < D_DIM; ++k) {
    float a0 = As[r0 + 0][k];
    float a1 = As[r0 + 1][k];
    float a2 = As[r0 + 2][k];
    float a3 = As[r0 + 3][k];
    float4 b = *reinterpret_cast<const float4*>(&Bs[k][c0]);
    acc[0][0] += a0 * b.x; acc[0][1] += a0 * b.y; acc[0][2] += a0 * b.z; acc[0][3] += a0 * b.w;
    acc[1][0] += a1 * b.x; acc[1][1] += a1 * b.y; acc[1][2] += a1 * b.z; acc[1][3] += a1 * b.w;
    acc[2][0] += a2 * b.x; acc[2][1] += a2 * b.y; acc[2][2] += a2 * b.z; acc[2][3] += a2 * b.w;
    acc[3][0] += a3 * b.x; acc[3][1] += a3 * b.y; acc[3][2] += a3 * b.z; acc[3][3] += a3 * b.w;
  }

  // Write the tile ONCE into the t=0 slice (k3 re-reads it: 9.4 MB, cache-hot).
  float* o = out + (size_t)h * S_DIM * S_DIM + (size_t)(by * 64 + r0) * S_DIM + bx * 64 + c0;
#pragma unroll
  for (int i = 0; i < 4; ++i) {
    *reinterpret_cast<float4*>(o + (size_t)i * S_DIM) =
        make_float4(acc[i][0], acc[i][1], acc[i][2], acc[i][3]);
  }
}

// Kernel 3: pure broadcast, FILL GEOMETRY (t-major). Block (cx, ty) owns a
// linear 64KB chunk of t-slice ty+1: thread does 4 cached reads of the t=0
// slice (L2/L3-hot, no HBM) + 4 nt stores, each store instr 1KB contiguous,
// write front advancing linearly within each slice — same shape as the
// rocclr fills that sustain 6.8-6.97 TB/s on this exact buffer.
// grid = (W_F4/1024, 62) = (576, 62), block = 256.
__global__ __launch_bounds__(256) void bcast_kernel(float* __restrict__ out) {
  const int i0 = blockIdx.x * 1024 + threadIdx.x;        // chunk base + lane
  const size_t toff = (size_t)(blockIdx.y + 1) * W_F4;   // t = 1..62
  const f32x4* src = reinterpret_cast<const f32x4*>(out);
  f32x4* dst = reinterpret_cast<f32x4*>(out) + toff;
#pragma unroll
  for (int q = 0; q < 4; ++q) {
    int i = i0 + q * 256;
    f32x4 v = src[i];
    __builtin_nontemporal_store(v, dst + i);
  }
}

extern "C" void kernel_launch(void* const* d_in, const int* in_sizes, int n_in,
                              void* d_out, int out_size, void* d_ws, size_t ws_size,
                              hipStream_t stream) {
  const float* x = (const float*)d_in[0];
  const float* y = (const float*)d_in[1];
  float* out = (float*)d_out;

  float* xb = (float*)d_ws;                 // 786432 floats
  float* yb = xb + SLICE_ELEMS;             // 786432 floats (6 MB total)

  treduce_kernel<<<dim3(2 * SLICE_F4 / 256), dim3(256), 0, stream>>>(x, y, xb, yb);
  gemm_kernel<<<dim3(6, 6, H_DIM), dim3(256), 0, stream>>>(xb, yb, out);
  bcast_kernel<<<dim3(W_F4 / 1024, T_DIM - 1), dim3(256), 0, stream>>>(out);
}